// Round 16
// baseline (191.961 us; speedup 1.0000x reference)
//
#include <hip/hip_runtime.h>
#include <hip/hip_fp16.h>

#define B 8
#define C 64
#define H 128
#define W 128
#define HW (H * W)
#define OC 27
#define KK 9
#define COUT 64
#define KDIM 576           // 9*64
#define LDSROW 1152        // bytes per pixel row (576 * 2B)
#define NPIX 16            // pixels per k_main workgroup
#define NPAIR (NPIX * KK)  // 144
#define WROWS 5
#define WCOLS 22
#define WRSTRIDE (WCOLS * 128)       // 2816 B per window row
#define WBYTES (WROWS * WRSTRIDE)    // 14080 B

typedef __attribute__((ext_vector_type(8))) short s16x8;
typedef __attribute__((ext_vector_type(4))) float f32x4;

__device__ inline ushort f2bf(float f) {
    union { float f; unsigned u; } uv;
    uv.f = f;
    unsigned r = uv.u + 0x7FFF + ((uv.u >> 16) & 1);
    return (ushort)(r >> 16);
}
__device__ inline float bf2f(ushort u) {
    return __uint_as_float((unsigned)u << 16);
}
__device__ inline unsigned pkhalf2(float a, float b) {
    __half2 h = __floats2half2_rn(a, b);
    return *(unsigned*)&h;
}

// ---------------------------------------------------------------------------
// Kernel 1: transpose x (NCHW fp32) -> xTb (NHWC bf16). XCD-chunked swizzle.
// ---------------------------------------------------------------------------
__global__ __launch_bounds__(256) void k_transpose_x(const float* __restrict__ x,
                                                     ushort* __restrict__ xTb) {
    __shared__ float lds[64][65];
    int j = blockIdx.x;
    int vb = (j & 7) * 256 + (j >> 3);
    int b = vb >> 8;
    int tile = vb & 255;
    int hw0 = tile * 64;
    int lane = threadIdx.x & 63;
    int cg = threadIdx.x >> 6;
#pragma unroll
    for (int r = 0; r < 16; ++r) {
        int c = cg * 16 + r;
        lds[c][lane] = x[(size_t)(b * C + c) * HW + hw0 + lane];
    }
    __syncthreads();
#pragma unroll
    for (int r = 0; r < 16; ++r) {
        int hwl = cg * 16 + r;
        xTb[(size_t)(b * HW + hw0 + hwl) * C + lane] = f2bf(lds[lane][hwl]);
    }
}

// ---------------------------------------------------------------------------
// Kernel 2: repack w -> wB[o][K] bf16, K = tap*64 + c.
// ---------------------------------------------------------------------------
__global__ __launch_bounds__(256) void k_prep_w(const float* __restrict__ w,
                                                ushort* __restrict__ wB) {
    int idx = blockIdx.x * 256 + threadIdx.x;
    if (idx >= COUT * KDIM) return;
    int o = idx / KDIM;
    int Kx = idx % KDIM;
    int k = Kx >> 6;
    int c = Kx & 63;
    wB[idx] = f2bf(w[(size_t)(o * C + c) * KK + k]);
}

// ---------------------------------------------------------------------------
// Kernel 2b: repack ow -> awB[32][576] bf16 (rows 27..31 = 0).
// ---------------------------------------------------------------------------
__global__ __launch_bounds__(256) void k_prep_aw(const float* __restrict__ ow,
                                                 ushort* __restrict__ awB) {
    int idx = blockIdx.x * 256 + threadIdx.x;
    if (idx >= 32 * KDIM) return;
    int o = idx / KDIM;
    int Kx = idx % KDIM;
    int tap = Kx >> 6;
    int c = Kx & 63;
    float v = (o < OC) ? ow[((size_t)o * C + c) * KK + tap] : 0.0f;
    awB[idx] = f2bf(v);
}

// ---------------------------------------------------------------------------
// Kernel 3: offset/mask conv (im2col MFMA GEMM); om written PIXEL-MAJOR
// [b][hw][32] (oc 27..31 zero-padded) via the existing LDS transpose.
// ---------------------------------------------------------------------------
__global__ __launch_bounds__(256) void k_om(const ushort* __restrict__ xTb,
                                            const ushort* __restrict__ awB,
                                            const float* __restrict__ ob,
                                            float* __restrict__ om_pm) {
    __shared__ __align__(16) char xwin[3 * 66 * 128];  // 25344 B
    int tid = threadIdx.x;
    int lane = tid & 63;
    int wv = tid >> 6;
    int j = blockIdx.x;
    int vb = (j & 7) * 256 + (j >> 3);
    int b = vb >> 8;
    int h = (vb >> 1) & 127;
    int w0 = (vb & 1) * 64;

    const ushort* xb = xTb + (size_t)b * (HW * C);
    int ch2 = tid & 31;
#pragma unroll
    for (int it = 0; it < 25; ++it) {
        int pi = it * 8 + (tid >> 5);
        if (pi < 198) {
            int row = pi / 66;
            int col = pi - row * 66;
            int y = h - 1 + row;
            int xc = w0 - 1 + col;
            unsigned v = 0;
            if ((unsigned)y < H && (unsigned)xc < W)
                v = *(const unsigned*)(xb + ((size_t)(y * W + xc) << 6) + ch2 * 2);
            int byte = (pi * 128 + ch2 * 4) ^ ((col & 7) << 4);
            *(unsigned*)(xwin + byte) = v;
        }
    }
    __syncthreads();

    f32x4 acc0 = {0.f, 0.f, 0.f, 0.f};
    f32x4 acc1 = {0.f, 0.f, 0.f, 0.f};
    int pixl = lane & 15;
    int q = lane >> 4;
    int base_col = wv * 16 + pixl;
    const ushort* a0 = awB + (size_t)pixl * KDIM + q * 8;
    const ushort* a1 = awB + (size_t)(16 + pixl) * KDIM + q * 8;
#pragma unroll
    for (int s = 0; s < 18; ++s) {
        int tap = s >> 1;
        int row = tap / 3;
        int cs = tap - row * 3;
        int col = base_col + cs;
        int c0b = ((s & 1) * 32 + q * 8) * 2;
        int byte = (((row * 66 + col) << 7) + c0b) ^ ((col & 7) << 4);
        s16x8 bfrag = *(const s16x8*)(xwin + byte);
        s16x8 af0 = *(const s16x8*)(a0 + s * 32);
        s16x8 af1 = *(const s16x8*)(a1 + s * 32);
        acc0 = __builtin_amdgcn_mfma_f32_16x16x32_bf16(af0, bfrag, acc0, 0, 0, 0);
        acc1 = __builtin_amdgcn_mfma_f32_16x16x32_bf16(af1, bfrag, acc1, 0, 0, 0);
    }

    __syncthreads();
    float* omt = (float*)xwin;  // [64 pix][29]
    {
        int pix = wv * 16 + pixl;
#pragma unroll
        for (int jj = 0; jj < 4; ++jj) {
            int oc = q * 4 + jj;
            omt[pix * 29 + oc] = acc0[jj] + ob[oc];
        }
#pragma unroll
        for (int jj = 0; jj < 4; ++jj) {
            int oc1 = 16 + q * 4 + jj;
            if (oc1 < OC) omt[pix * 29 + oc1] = acc1[jj] + ob[oc1];
        }
    }
    __syncthreads();

    float* dst = om_pm + ((size_t)b * HW + h * W + w0) * 32;
#pragma unroll
    for (int t = tid; t < 64 * 32; t += 256) {
        int pix = t >> 5;
        int oc = t & 31;
        float v = (oc < OC) ? omt[pix * 29 + oc] : 0.0f;
        dst[(size_t)pix * 32 + oc] = v;
    }
}

// ---------------------------------------------------------------------------
// Kernel 4: fused deformable sampling + MFMA einsum, LDS-WINDOW sampler.
//  Stage: rows [h-2,h+2] x cols [w0-3,w0+18] x 64ch bf16 -> win (14080 B),
//         ~14 dwordx4 wave-loads per block (zero-fill outside image).
//  A0: per (pixel,tap): 4 f16 slot weights + packed ushort2 offsets:
//      in-window -> window byte offsets; else bit15 flag + global off>>7.
//  A1: per pair: 2 ds_read_b32 (conflict-free) or global fallback; blend,
//      shfl_xor(32), cvt_pk, half-wave ds_write into swizzled samp.
//  B : 18 x mfma_f32_16x16x32_bf16 per wave (unchanged).
// ---------------------------------------------------------------------------
__global__ __launch_bounds__(256) void k_main(const ushort* __restrict__ xTb,
                                              const float* __restrict__ om_pm,
                                              const ushort* __restrict__ wB,
                                              const float* __restrict__ bias,
                                              float* __restrict__ out) {
    __shared__ __align__(16) char smem[NPIX * LDSROW];  // 18432 B
    __shared__ __align__(16) char win[WBYTES];          // 14080 B
    __shared__ uint2 mw_lds[NPAIR];                     // 1152 B
    __shared__ ushort2 mo_lds[NPAIR];                   // 576 B

    int tid = threadIdx.x;
    int lane = tid & 63;
    int wv = tid >> 6;
    int jb = blockIdx.x;
    int vb = (jb & 7) * 1024 + (jb >> 3);  // batch b -> XCD b
    int pb = vb * NPIX;
    int b = pb >> 14;
    int rem = pb & (HW - 1);
    int h = rem >> 7;
    int w0 = rem & (W - 1);

    const char* xbase = (const char*)(xTb + (size_t)b * (HW * C));

    // ---- window staging: 5 rows x 22 cols x 128B, zero-filled OOB ----
    {
        int y0w = h - 2, c0w = w0 - 3;
#pragma unroll
        for (int i = 0; i < 4; ++i) {
            int idx = i * 256 + tid;  // 16B chunks: 880 total
            if (idx < WROWS * WCOLS * 8) {
                int wrow = idx / (WCOLS * 8);
                int rem16 = idx - wrow * (WCOLS * 8);
                int wcol = rem16 >> 3;
                int ch16 = rem16 & 7;
                int y = y0w + wrow, cx = c0w + wcol;
                uint4 v = make_uint4(0, 0, 0, 0);
                if ((unsigned)y < H && (unsigned)cx < W)
                    v = *(const uint4*)(xbase + (((y << 7) + cx) << 7) + ch16 * 16);
                *(uint4*)(win + wrow * WRSTRIDE + wcol * 128 + ch16 * 16) = v;
            }
        }
    }

    // ---- Phase A0: per-(pixel,tap) metadata ----
    if (tid < NPAIR) {
        int pix = tid / 9;
        int k = tid - pix * 9;
        const float* o0 = om_pm + ((size_t)b * HW + rem + pix) * 32;
        float offx = o0[k];
        float offy = o0[9 + k];
        float mlog = o0[18 + k];
        int dh = k / 3 - 1;
        int dw = k % 3 - 1;
        float mask = 1.0f / (1.0f + __expf(-mlog));
        float gx = (float)(w0 + pix + dw) + offx;
        float gy = (float)(h + dh) + offy;
        float x0f = floorf(gx), y0f = floorf(gy);
        int x0 = (int)x0f, y0 = (int)y0f;
        int x1 = x0 + 1, y1 = y0 + 1;
        float wx1 = gx - x0f, wy1 = gy - y0f;
        float wx0 = 1.0f - wx1, wy0 = 1.0f - wy1;
        float rw0 = ((unsigned)y0 < H) ? wy0 * mask : 0.0f;
        float rw1 = ((unsigned)y1 < H) ? wy1 * mask : 0.0f;
        int y0c = min(max(y0, 0), H - 1), y1c = min(max(y1, 0), H - 1);
        int colbase = min(max(x0, 0), W - 2);
        float cw0 = 0.0f, cw1 = 0.0f;
        if ((unsigned)x0 < W) { if (x0 == colbase) cw0 += wx0; else cw1 += wx0; }
        if ((unsigned)x1 < W) { if (x1 == colbase) cw0 += wx1; else cw1 += wx1; }
        mw_lds[tid] = make_uint2(pkhalf2(rw0 * cw0, rw0 * cw1),
                                 pkhalf2(rw1 * cw0, rw1 * cw1));
        int iy0w = y0c - (h - 2), iy1w = y1c - (h - 2), icw = colbase - (w0 - 3);
        bool inw = ((unsigned)iy0w < WROWS) && ((unsigned)iy1w < WROWS) &&
                   ((unsigned)icw <= WCOLS - 2);
        if (inw) {
            mo_lds[tid] = make_ushort2((ushort)(iy0w * WRSTRIDE + icw * 128),
                                       (ushort)(iy1w * WRSTRIDE + icw * 128));
        } else {
            mo_lds[tid] = make_ushort2(
                (ushort)(0x8000u | (unsigned)((y0c << 7) + colbase)),
                (ushort)((y1c << 7) + colbase));
        }
    }
    __syncthreads();

    // ---- Phase A1: window ds_read gathers (global fallback if flagged) ----
    bool lo_half = lane < 32;
#pragma unroll 1
    for (int pp = 0; pp < 4; ++pp) {
        int p = wv * 4 + pp;
        int vlds = p * LDSROW + (((lane & 31) * 4) ^ ((p & 7) << 4));
#pragma unroll
        for (int k = 0; k < KK; ++k) {
            uint2 mwv = mw_lds[p * 9 + k];
            ushort2 mo = mo_lds[p * 9 + k];
            unsigned d0, d1;
            if (mo.x & 0x8000u) {  // rare fallback: per-pair uniform branch
                d0 = *(const unsigned*)(xbase + ((int)(mo.x & 0x7FFFu) << 7) + lane * 4);
                d1 = *(const unsigned*)(xbase + ((int)mo.y << 7) + lane * 4);
            } else {
                d0 = *(const unsigned*)(win + mo.x + lane * 4);
                d1 = *(const unsigned*)(win + mo.y + lane * 4);
            }
            __half2 h0 = *(__half2*)&mwv.x;
            __half2 h1 = *(__half2*)&mwv.y;
            float wa = lo_half ? __half2float(h0.x) : __half2float(h0.y);
            float wb_ = lo_half ? __half2float(h1.x) : __half2float(h1.y);
            float a0 = __uint_as_float(d0 << 16);
            float a1 = __uint_as_float(d0 & 0xFFFF0000u);
            float b0 = __uint_as_float(d1 << 16);
            float b1 = __uint_as_float(d1 & 0xFFFF0000u);
            float p0 = a0 * wa + b0 * wb_;
            float p1 = a1 * wa + b1 * wb_;
            float q0 = __shfl_xor(p0, 32, 64);
            float q1 = __shfl_xor(p1, 32, 64);
            float s0 = p0 + q0, s1 = p1 + q1;
            unsigned pk;
            asm("v_cvt_pk_bf16_f32 %0, %1, %2" : "=v"(pk) : "v"(s0), "v"(s1));
            if (lane < 32) *(unsigned*)(smem + vlds + k * 128) = pk;
        }
    }
    __syncthreads();

    // ---- Phase B: MFMA ----
    f32x4 acc;
#pragma unroll
    for (int j = 0; j < 4; ++j) acc[j] = bias[wv * 16 + (lane >> 4) * 4 + j];

    int pix = lane & 15;
    const ushort* wrow = wB + (size_t)(wv * 16 + pix) * KDIM + (lane >> 4) * 8;
#pragma unroll
    for (int s = 0; s < 18; ++s) {
        int kbyte = s * 64 + (lane >> 4) * 16;
        int byte = (pix * LDSROW + kbyte) ^ ((pix & 7) << 4);
        s16x8 bfrag = *(const s16x8*)(smem + byte);
        s16x8 afrag = *(const s16x8*)(wrow + s * 32);
        acc = __builtin_amdgcn_mfma_f32_16x16x32_bf16(afrag, bfrag, acc, 0, 0, 0);
    }

    float* obase = out + ((size_t)(b * COUT + wv * 16 + (lane >> 4) * 4) * HW) + h * W + w0;
#pragma unroll
    for (int j = 0; j < 4; ++j) obase[(size_t)j * HW + pix] = acc[j];
}

// ---------------------------------------------------------------------------
extern "C" void kernel_launch(void* const* d_in, const int* in_sizes, int n_in,
                              void* d_out, int out_size, void* d_ws, size_t ws_size,
                              hipStream_t stream) {
    const float* x = (const float*)d_in[0];
    const float* ow = (const float*)d_in[1];
    const float* ob = (const float*)d_in[2];
    const float* w = (const float*)d_in[3];
    const float* bias = (const float*)d_in[4];
    float* out = (float*)d_out;

    float* om_pm = (float*)d_ws;                          // B*HW*32 f = 16.8 MB
    ushort* xTb = (ushort*)(om_pm + (size_t)B * HW * 32); // B*HW*C ushort = 16.8 MB
    ushort* wB = xTb + (size_t)B * HW * C;                // 36864 ushort
    ushort* awB = wB + (size_t)COUT * KDIM;               // 18432 ushort
    // total ~33.7 MB

    hipLaunchKernelGGL(k_transpose_x, dim3(B * 256), dim3(256), 0, stream, x, xTb);
    hipLaunchKernelGGL(k_prep_w, dim3((COUT * KDIM + 255) / 256), dim3(256), 0,
                       stream, w, wB);
    hipLaunchKernelGGL(k_prep_aw, dim3((32 * KDIM + 255) / 256), dim3(256), 0,
                       stream, ow, awB);
    hipLaunchKernelGGL(k_om, dim3(B * H * 2), dim3(256), 0, stream, xTb, awB, ob, om_pm);
    hipLaunchKernelGGL(k_main, dim3(B * HW / NPIX), dim3(256), 0, stream,
                       xTb, om_pm, wB, bias, out);
}

// Round 17
// 156.447 us; speedup vs baseline: 1.2270x; 1.2270x over previous
//
#include <hip/hip_runtime.h>
#include <hip/hip_fp16.h>

#define B 8
#define C 64
#define H 128
#define W 128
#define HW (H * W)
#define OC 27
#define KK 9
#define COUT 64
#define KDIM 576           // 9*64
#define LDSROW 1152        // bytes per pixel row (576 * 2B)
#define NPIX 16            // pixels per k_main workgroup
#define NPAIR (NPIX * KK)  // 144

typedef __attribute__((ext_vector_type(8))) short s16x8;
typedef __attribute__((ext_vector_type(4))) float f32x4;

__device__ inline ushort f2bf(float f) {
    union { float f; unsigned u; } uv;
    uv.f = f;
    unsigned r = uv.u + 0x7FFF + ((uv.u >> 16) & 1);
    return (ushort)(r >> 16);
}
__device__ inline float bf2f(ushort u) {
    return __uint_as_float((unsigned)u << 16);
}
__device__ inline unsigned pkhalf2(float a, float b) {
    __half2 h = __floats2half2_rn(a, b);
    return *(unsigned*)&h;
}

// ---------------------------------------------------------------------------
// Kernel 1: transpose x (NCHW fp32) -> xTb (NHWC bf16). XCD-chunked swizzle.
// Stores vectorized: ushort2 per lane (2 channels), 2 hw-rows per wave-instr.
// ---------------------------------------------------------------------------
__global__ __launch_bounds__(256) void k_transpose_x(const float* __restrict__ x,
                                                     ushort* __restrict__ xTb) {
    __shared__ float lds[64][65];
    int j = blockIdx.x;
    int vb = (j & 7) * 256 + (j >> 3);
    int b = vb >> 8;
    int tile = vb & 255;
    int hw0 = tile * 64;
    int lane = threadIdx.x & 63;
    int cg = threadIdx.x >> 6;
#pragma unroll
    for (int r = 0; r < 16; ++r) {
        int c = cg * 16 + r;
        lds[c][lane] = x[(size_t)(b * C + c) * HW + hw0 + lane];
    }
    __syncthreads();
    int c2 = (lane & 31) * 2;
#pragma unroll
    for (int r = 0; r < 8; ++r) {
        int hwl = cg * 16 + r * 2 + (lane >> 5);
        ushort2 v;
        v.x = f2bf(lds[c2][hwl]);
        v.y = f2bf(lds[c2 + 1][hwl]);
        *(ushort2*)&xTb[(size_t)(b * HW + hw0 + hwl) * C + c2] = v;
    }
}

// ---------------------------------------------------------------------------
// Kernel 2: repack w -> wB[o][K] bf16, K = tap*64 + c.
// ---------------------------------------------------------------------------
__global__ __launch_bounds__(256) void k_prep_w(const float* __restrict__ w,
                                                ushort* __restrict__ wB) {
    int idx = blockIdx.x * 256 + threadIdx.x;
    if (idx >= COUT * KDIM) return;
    int o = idx / KDIM;
    int Kx = idx % KDIM;
    int k = Kx >> 6;
    int c = Kx & 63;
    wB[idx] = f2bf(w[(size_t)(o * C + c) * KK + k]);
}

// ---------------------------------------------------------------------------
// Kernel 2b: repack ow -> awB[32][576] bf16 (rows 27..31 = 0).
// ---------------------------------------------------------------------------
__global__ __launch_bounds__(256) void k_prep_aw(const float* __restrict__ ow,
                                                 ushort* __restrict__ awB) {
    int idx = blockIdx.x * 256 + threadIdx.x;
    if (idx >= 32 * KDIM) return;
    int o = idx / KDIM;
    int Kx = idx % KDIM;
    int tap = Kx >> 6;
    int c = Kx & 63;
    float v = (o < OC) ? ow[((size_t)o * C + c) * KK + tap] : 0.0f;
    awB[idx] = f2bf(v);
}

// ---------------------------------------------------------------------------
// Kernel 3: offset/mask conv (im2col MFMA GEMM); staging vectorized to
// uint4 (7 dwordx4 per thread vs 25 dword). om written pixel-major [b][hw][32].
// ---------------------------------------------------------------------------
__global__ __launch_bounds__(256) void k_om(const ushort* __restrict__ xTb,
                                            const ushort* __restrict__ awB,
                                            const float* __restrict__ ob,
                                            float* __restrict__ om_pm) {
    __shared__ __align__(16) char xwin[3 * 66 * 128];  // 25344 B
    int tid = threadIdx.x;
    int lane = tid & 63;
    int wv = tid >> 6;
    int j = blockIdx.x;
    int vb = (j & 7) * 256 + (j >> 3);
    int b = vb >> 8;
    int h = (vb >> 1) & 127;
    int w0 = (vb & 1) * 64;

    const char* xb = (const char*)(xTb + (size_t)b * (HW * C));
    // ---- stage 3x66 positions x 128B each, as 16B chunks: 1584 total ----
#pragma unroll
    for (int i = 0; i < 7; ++i) {
        int idx = i * 256 + tid;
        if (idx < 198 * 8) {
            int pi = idx >> 3;       // position index
            int ch16 = idx & 7;      // 16B chunk within 128B
            int row = pi / 66;
            int col = pi - row * 66;
            int y = h - 1 + row;
            int xc = w0 - 1 + col;
            uint4 v = make_uint4(0, 0, 0, 0);
            if ((unsigned)y < H && (unsigned)xc < W)
                v = *(const uint4*)(xb + ((size_t)((y << 7) + xc) << 7) + ch16 * 16);
            int byte = (pi * 128 + ch16 * 16) ^ ((col & 7) << 4);
            *(uint4*)(xwin + byte) = v;
        }
    }
    __syncthreads();

    f32x4 acc0 = {0.f, 0.f, 0.f, 0.f};
    f32x4 acc1 = {0.f, 0.f, 0.f, 0.f};
    int pixl = lane & 15;
    int q = lane >> 4;
    int base_col = wv * 16 + pixl;
    const ushort* a0 = awB + (size_t)pixl * KDIM + q * 8;
    const ushort* a1 = awB + (size_t)(16 + pixl) * KDIM + q * 8;
#pragma unroll
    for (int s = 0; s < 18; ++s) {
        int tap = s >> 1;
        int row = tap / 3;
        int cs = tap - row * 3;
        int col = base_col + cs;
        int c0b = ((s & 1) * 32 + q * 8) * 2;
        int byte = (((row * 66 + col) << 7) + c0b) ^ ((col & 7) << 4);
        s16x8 bfrag = *(const s16x8*)(xwin + byte);
        s16x8 af0 = *(const s16x8*)(a0 + s * 32);
        s16x8 af1 = *(const s16x8*)(a1 + s * 32);
        acc0 = __builtin_amdgcn_mfma_f32_16x16x32_bf16(af0, bfrag, acc0, 0, 0, 0);
        acc1 = __builtin_amdgcn_mfma_f32_16x16x32_bf16(af1, bfrag, acc1, 0, 0, 0);
    }

    __syncthreads();
    float* omt = (float*)xwin;  // [64 pix][29]
    {
        int pix = wv * 16 + pixl;
#pragma unroll
        for (int jj = 0; jj < 4; ++jj) {
            int oc = q * 4 + jj;
            omt[pix * 29 + oc] = acc0[jj] + ob[oc];
        }
#pragma unroll
        for (int jj = 0; jj < 4; ++jj) {
            int oc1 = 16 + q * 4 + jj;
            if (oc1 < OC) omt[pix * 29 + oc1] = acc1[jj] + ob[oc1];
        }
    }
    __syncthreads();

    float* dst = om_pm + ((size_t)b * HW + h * W + w0) * 32;
#pragma unroll
    for (int t = tid; t < 64 * 32; t += 256) {
        int pix = t >> 5;
        int oc = t & 31;
        float v = (oc < OC) ? omt[pix * 29 + oc] : 0.0f;
        dst[(size_t)pix * 32 + oc] = v;
    }
}

// ---------------------------------------------------------------------------
// Kernel 4: fused deformable sampling + MFMA einsum (R14 best: 111.7 µs,
// 20480 B LDS). Unchanged this round.
// ---------------------------------------------------------------------------
__global__ __launch_bounds__(256) void k_main(const ushort* __restrict__ xTb,
                                              const float* __restrict__ om_pm,
                                              const ushort* __restrict__ wB,
                                              const float* __restrict__ bias,
                                              float* __restrict__ out) {
    __shared__ __align__(16) char smem[NPIX * LDSROW];  // 18432 B
    __shared__ uint2 mw_lds[NPAIR];                     // 1152 B (f16x4)
    __shared__ ushort2 mo_lds[NPAIR];                   // 576 B  (off>>7)

    int tid = threadIdx.x;
    int lane = tid & 63;
    int wv = tid >> 6;
    int jb = blockIdx.x;
    int vb = (jb & 7) * 1024 + (jb >> 3);  // batch b -> XCD b
    int pb = vb * NPIX;
    int b = pb >> 14;
    int rem = pb & (HW - 1);
    int h = rem >> 7;
    int w0 = rem & (W - 1);

    // ---- Phase A0: per-(pixel,tap) slot metadata from pixel-major om ----
    if (tid < NPAIR) {
        int pix = tid / 9;
        int k = tid - pix * 9;
        const float* o0 = om_pm + ((size_t)b * HW + rem + pix) * 32;
        float offx = o0[k];
        float offy = o0[9 + k];
        float mlog = o0[18 + k];
        int dh = k / 3 - 1;
        int dw = k % 3 - 1;
        float mask = 1.0f / (1.0f + __expf(-mlog));
        float gx = (float)(w0 + pix + dw) + offx;
        float gy = (float)(h + dh) + offy;
        float x0f = floorf(gx), y0f = floorf(gy);
        int x0 = (int)x0f, y0 = (int)y0f;
        int x1 = x0 + 1, y1 = y0 + 1;
        float wx1 = gx - x0f, wy1 = gy - y0f;
        float wx0 = 1.0f - wx1, wy0 = 1.0f - wy1;
        float rw0 = ((unsigned)y0 < H) ? wy0 * mask : 0.0f;
        float rw1 = ((unsigned)y1 < H) ? wy1 * mask : 0.0f;
        int y0c = min(max(y0, 0), H - 1), y1c = min(max(y1, 0), H - 1);
        int colbase = min(max(x0, 0), W - 2);
        float cw0 = 0.0f, cw1 = 0.0f;
        if ((unsigned)x0 < W) { if (x0 == colbase) cw0 += wx0; else cw1 += wx0; }
        if ((unsigned)x1 < W) { if (x1 == colbase) cw0 += wx1; else cw1 += wx1; }
        mw_lds[tid] = make_uint2(pkhalf2(rw0 * cw0, rw0 * cw1),
                                 pkhalf2(rw1 * cw0, rw1 * cw1));
        mo_lds[tid] = make_ushort2((ushort)(((y0c * W + colbase) * (C * 2)) >> 7),
                                   (ushort)(((y1c * W + colbase) * (C * 2)) >> 7));
    }
    __syncthreads();

    // ---- Phase A1: batched full-wave row gathers ----
    const char* xbase = (const char*)(xTb + (size_t)b * (HW * C));
    bool lo_half = lane < 32;
#pragma unroll 1
    for (int pp = 0; pp < 4; ++pp) {
        int p = wv * 4 + pp;
        uint2 mwv[KK];
        int mo0[KK], mo1[KK];
#pragma unroll
        for (int k = 0; k < KK; ++k) {
            mwv[k] = mw_lds[p * 9 + k];
            ushort2 mo = mo_lds[p * 9 + k];
            mo0[k] = (int)mo.x << 7;
            mo1[k] = (int)mo.y << 7;
        }
        unsigned d0[KK], d1[KK];
#pragma unroll
        for (int k = 0; k < KK; ++k) {
            d0[k] = *(const unsigned*)(xbase + mo0[k] + lane * 4);
            d1[k] = *(const unsigned*)(xbase + mo1[k] + lane * 4);
        }
        __builtin_amdgcn_sched_barrier(0);
        int vlds = p * LDSROW + (((lane & 31) * 4) ^ ((p & 7) << 4));
#pragma unroll
        for (int k = 0; k < KK; ++k) {
            __half2 h0 = *(__half2*)&mwv[k].x;
            __half2 h1 = *(__half2*)&mwv[k].y;
            float wa = lo_half ? __half2float(h0.x) : __half2float(h0.y);
            float wb_ = lo_half ? __half2float(h1.x) : __half2float(h1.y);
            float a0 = __uint_as_float(d0[k] << 16);
            float a1 = __uint_as_float(d0[k] & 0xFFFF0000u);
            float b0 = __uint_as_float(d1[k] << 16);
            float b1 = __uint_as_float(d1[k] & 0xFFFF0000u);
            float p0 = a0 * wa + b0 * wb_;
            float p1 = a1 * wa + b1 * wb_;
            float q0 = __shfl_xor(p0, 32, 64);
            float q1 = __shfl_xor(p1, 32, 64);
            float s0 = p0 + q0, s1 = p1 + q1;
            unsigned pk;
            asm("v_cvt_pk_bf16_f32 %0, %1, %2" : "=v"(pk) : "v"(s0), "v"(s1));
            if (lane < 32) *(unsigned*)(smem + vlds + k * 128) = pk;
        }
    }
    __syncthreads();

    // ---- Phase B: MFMA ----
    f32x4 acc;
#pragma unroll
    for (int j = 0; j < 4; ++j) acc[j] = bias[wv * 16 + (lane >> 4) * 4 + j];

    int pix = lane & 15;
    const ushort* wrow = wB + (size_t)(wv * 16 + pix) * KDIM + (lane >> 4) * 8;
#pragma unroll
    for (int s = 0; s < 18; ++s) {
        int kbyte = s * 64 + (lane >> 4) * 16;
        int byte = (pix * LDSROW + kbyte) ^ ((pix & 7) << 4);
        s16x8 bfrag = *(const s16x8*)(smem + byte);
        s16x8 afrag = *(const s16x8*)(wrow + s * 32);
        acc = __builtin_amdgcn_mfma_f32_16x16x32_bf16(afrag, bfrag, acc, 0, 0, 0);
    }

    float* obase = out + ((size_t)(b * COUT + wv * 16 + (lane >> 4) * 4) * HW) + h * W + w0;
#pragma unroll
    for (int j = 0; j < 4; ++j) obase[(size_t)j * HW + pix] = acc[j];
}

// ---------------------------------------------------------------------------
extern "C" void kernel_launch(void* const* d_in, const int* in_sizes, int n_in,
                              void* d_out, int out_size, void* d_ws, size_t ws_size,
                              hipStream_t stream) {
    const float* x = (const float*)d_in[0];
    const float* ow = (const float*)d_in[1];
    const float* ob = (const float*)d_in[2];
    const float* w = (const float*)d_in[3];
    const float* bias = (const float*)d_in[4];
    float* out = (float*)d_out;

    float* om_pm = (float*)d_ws;                          // B*HW*32 f = 16.8 MB
    ushort* xTb = (ushort*)(om_pm + (size_t)B * HW * 32); // B*HW*C ushort = 16.8 MB
    ushort* wB = xTb + (size_t)B * HW * C;                // 36864 ushort
    ushort* awB = wB + (size_t)COUT * KDIM;               // 18432 ushort
    // total ~33.7 MB

    hipLaunchKernelGGL(k_transpose_x, dim3(B * 256), dim3(256), 0, stream, x, xTb);
    hipLaunchKernelGGL(k_prep_w, dim3((COUT * KDIM + 255) / 256), dim3(256), 0,
                       stream, w, wB);
    hipLaunchKernelGGL(k_prep_aw, dim3((32 * KDIM + 255) / 256), dim3(256), 0,
                       stream, ow, awB);
    hipLaunchKernelGGL(k_om, dim3(B * H * 2), dim3(256), 0, stream, xTb, awB, ob, om_pm);
    hipLaunchKernelGGL(k_main, dim3(B * HW / NPIX), dim3(256), 0, stream,
                       xTb, om_pm, wB, bias, out);
}